// Round 7
// baseline (137.224 us; speedup 1.0000x reference)
//
#include <hip/hip_runtime.h>

// BiasAddLayerNormFP8: bda = residual + (x + bias); LayerNorm over H=1024;
// outputs: [bda2 f32 | fp8(ln) dequantized to f32 | amax scalar], all float32.
//
// R7: R6's 3-row straight-line structure + amdgpu_waves_per_eu(4,4). R6's
// failure mode: compiler's occupancy heuristic targeted 8 waves/EU (VGPR=64)
// and serialized the 24-load block via waitcnt+reg-reuse. Pinning waves/EU to
// exactly 4 gives the allocator a real 128-VGPR budget so all 24 float4 loads
// (384B/lane) genuinely stay in flight across the reduce chains.
// Numerics bit-identical to the passing R2/R5 chain.

constexpr int H = 1024;
constexpr int CHUNKS = 4;            // 4 x float4 x 64 lanes = 1024 cols
constexpr float EPS = 1e-5f;
constexpr float FP8_MAX = 448.0f;
constexpr float INV_H = 1.0f / 1024.0f;

__device__ __forceinline__ float waveReduceMax(float v) {
#pragma unroll
    for (int off = 32; off > 0; off >>= 1) v = fmaxf(v, __shfl_down(v, off));
    return v;
}

__device__ __forceinline__ float waveAllReduceSum(float v) {
#pragma unroll
    for (int off = 1; off < 64; off <<= 1) v += __shfl_xor(v, off);
    return v;
}

__device__ __forceinline__ void quantChunk(
    const float (&d)[4], float rsigma, const float4& gv, const float4& tv,
    float* __restrict__ dst, float& localAmax)
{
    const float l0 = d[0] * rsigma * gv.x + tv.x;
    const float l1 = d[1] * rsigma * gv.y + tv.y;
    const float l2 = d[2] * rsigma * gv.z + tv.z;
    const float l3 = d[3] * rsigma * gv.w + tv.w;

    localAmax = fmaxf(localAmax,
        fmaxf(fmaxf(fabsf(l0), fabsf(l1)), fmaxf(fabsf(l2), fabsf(l3))));

    const float c0 = fminf(fmaxf(l0, -FP8_MAX), FP8_MAX);
    const float c1 = fminf(fmaxf(l1, -FP8_MAX), FP8_MAX);
    const float c2 = fminf(fmaxf(l2, -FP8_MAX), FP8_MAX);
    const float c3 = fminf(fmaxf(l3, -FP8_MAX), FP8_MAX);
    const int p01 = __builtin_amdgcn_cvt_pk_fp8_f32(c0, c1, 0, false);
    const int p23 = __builtin_amdgcn_cvt_pk_fp8_f32(c2, c3, 0, false);
    float4 qv;
    qv.x = __builtin_amdgcn_cvt_f32_fp8(p01, 0);
    qv.y = __builtin_amdgcn_cvt_f32_fp8(p01, 1);
    qv.z = __builtin_amdgcn_cvt_f32_fp8(p23, 0);
    qv.w = __builtin_amdgcn_cvt_f32_fp8(p23, 1);
    *reinterpret_cast<float4*>(dst) = qv;
}

// Single-row path (tail rows when n_rows % 3 != 0). Same numerics.
__device__ __forceinline__ void processOneRow(
    int row, int col0,
    const float* __restrict__ x, const float* __restrict__ residual,
    const float* __restrict__ bias, const float* __restrict__ gamma,
    const float* __restrict__ beta,
    float* __restrict__ out_bda, float* __restrict__ out_q, float& localAmax)
{
    const size_t rbase = (size_t)row * H;
    float bda[CHUNKS][4];
    float s = 0.0f;
#pragma unroll
    for (int c = 0; c < CHUNKS; ++c) {
        const int col = col0 + c * 256;
        const float4 xv = *reinterpret_cast<const float4*>(x + rbase + col);
        const float4 rv = *reinterpret_cast<const float4*>(residual + rbase + col);
        const float4 bv = *reinterpret_cast<const float4*>(bias + col);
        bda[c][0] = rv.x + (xv.x + bv.x);
        bda[c][1] = rv.y + (xv.y + bv.y);
        bda[c][2] = rv.z + (xv.z + bv.z);
        bda[c][3] = rv.w + (xv.w + bv.w);
        *reinterpret_cast<float4*>(out_bda + rbase + col) =
            make_float4(bda[c][0], bda[c][1], bda[c][2], bda[c][3]);
        s += (bda[c][0] + bda[c][1]) + (bda[c][2] + bda[c][3]);
    }
    const float mu = waveAllReduceSum(s) * INV_H;
    float ss = 0.0f;
#pragma unroll
    for (int c = 0; c < CHUNKS; ++c)
#pragma unroll
        for (int j = 0; j < 4; ++j) { bda[c][j] -= mu; ss += bda[c][j] * bda[c][j]; }
    ss = waveAllReduceSum(ss);
    const float rsigma = 1.0f / sqrtf(ss * INV_H + EPS);
#pragma unroll
    for (int c = 0; c < CHUNKS; ++c) {
        const int col = col0 + c * 256;
        const float4 gv = *reinterpret_cast<const float4*>(gamma + col);
        const float4 tv = *reinterpret_cast<const float4*>(beta + col);
        quantChunk(bda[c], rsigma, gv, tv, out_q + rbase + col, localAmax);
    }
}

__global__ __launch_bounds__(256)
__attribute__((amdgpu_waves_per_eu(4, 4)))
void fused_bda_ln_fp8(
    const float* __restrict__ x,
    const float* __restrict__ bias,
    const float* __restrict__ residual,
    const float* __restrict__ gamma,
    const float* __restrict__ beta,
    float* __restrict__ out_bda,
    float* __restrict__ out_q,
    unsigned int* __restrict__ out_amax,
    int n_rows)
{
    const int tid = threadIdx.x;      // 256 threads = 4 waves
    const int lane = tid & 63;
    const int wid = tid >> 6;
    const int col0 = lane * 4;
    const int gw = blockIdx.x * 4 + wid;     // global wave id
    const int gwaves = gridDim.x * 4;

    float localAmax = 0.0f;
    __shared__ float red[4];

    const int triples = n_rows / 3;

#pragma unroll 1
    for (int t = gw; t < triples; t += gwaves) {
        const size_t b0 = (size_t)(3 * t) * H;
        const size_t b1 = b0 + H;
        const size_t b2 = b1 + H;

        // ---- issue ALL 24 loads, row-major (row0's 8 first -> vmcnt releases
        //      row0 consume while rows 1-2 still fly). One basic block. ----
        float4 xa[CHUNKS], ra[CHUNKS], xb[CHUNKS], rb[CHUNKS], xc[CHUNKS], rc[CHUNKS];
#pragma unroll
        for (int c = 0; c < CHUNKS; ++c) {
            const int col = col0 + c * 256;
            xa[c] = *reinterpret_cast<const float4*>(x + b0 + col);
            ra[c] = *reinterpret_cast<const float4*>(residual + b0 + col);
        }
#pragma unroll
        for (int c = 0; c < CHUNKS; ++c) {
            const int col = col0 + c * 256;
            xb[c] = *reinterpret_cast<const float4*>(x + b1 + col);
            rb[c] = *reinterpret_cast<const float4*>(residual + b1 + col);
        }
#pragma unroll
        for (int c = 0; c < CHUNKS; ++c) {
            const int col = col0 + c * 256;
            xc[c] = *reinterpret_cast<const float4*>(x + b2 + col);
            rc[c] = *reinterpret_cast<const float4*>(residual + b2 + col);
        }
        __builtin_amdgcn_sched_barrier(0);   // pin load issue above everything below

        // ---- consume row by row (releases each row's load regs in turn) ----
        float A[CHUNKS][4], B[CHUNKS][4], C[CHUNKS][4];
        float s0 = 0.0f, s1 = 0.0f, s2 = 0.0f;
#pragma unroll
        for (int c = 0; c < CHUNKS; ++c) {
            const int col = col0 + c * 256;
            const float4 bv = *reinterpret_cast<const float4*>(bias + col);
            A[c][0] = ra[c].x + (xa[c].x + bv.x);
            A[c][1] = ra[c].y + (xa[c].y + bv.y);
            A[c][2] = ra[c].z + (xa[c].z + bv.z);
            A[c][3] = ra[c].w + (xa[c].w + bv.w);
            *reinterpret_cast<float4*>(out_bda + b0 + col) =
                make_float4(A[c][0], A[c][1], A[c][2], A[c][3]);
            s0 += (A[c][0] + A[c][1]) + (A[c][2] + A[c][3]);
        }
#pragma unroll
        for (int c = 0; c < CHUNKS; ++c) {
            const int col = col0 + c * 256;
            const float4 bv = *reinterpret_cast<const float4*>(bias + col);
            B[c][0] = rb[c].x + (xb[c].x + bv.x);
            B[c][1] = rb[c].y + (xb[c].y + bv.y);
            B[c][2] = rb[c].z + (xb[c].z + bv.z);
            B[c][3] = rb[c].w + (xb[c].w + bv.w);
            *reinterpret_cast<float4*>(out_bda + b1 + col) =
                make_float4(B[c][0], B[c][1], B[c][2], B[c][3]);
            s1 += (B[c][0] + B[c][1]) + (B[c][2] + B[c][3]);
        }
#pragma unroll
        for (int c = 0; c < CHUNKS; ++c) {
            const int col = col0 + c * 256;
            const float4 bv = *reinterpret_cast<const float4*>(bias + col);
            C[c][0] = rc[c].x + (xc[c].x + bv.x);
            C[c][1] = rc[c].y + (xc[c].y + bv.y);
            C[c][2] = rc[c].z + (xc[c].z + bv.z);
            C[c][3] = rc[c].w + (xc[c].w + bv.w);
            *reinterpret_cast<float4*>(out_bda + b2 + col) =
                make_float4(C[c][0], C[c][1], C[c][2], C[c][3]);
            s2 += (C[c][0] + C[c][1]) + (C[c][2] + C[c][3]);
        }

        // ---- mean: three independent butterflies, interleaved ----
#pragma unroll
        for (int off = 1; off < 64; off <<= 1) {
            s0 += __shfl_xor(s0, off);
            s1 += __shfl_xor(s1, off);
            s2 += __shfl_xor(s2, off);
        }
        const float mu0 = s0 * INV_H;
        const float mu1 = s1 * INV_H;
        const float mu2 = s2 * INV_H;

        // ---- variance, two-pass, all rows ----
        float ss0 = 0.0f, ss1 = 0.0f, ss2 = 0.0f;
#pragma unroll
        for (int c = 0; c < CHUNKS; ++c) {
#pragma unroll
            for (int j = 0; j < 4; ++j) {
                A[c][j] -= mu0; ss0 += A[c][j] * A[c][j];
                B[c][j] -= mu1; ss1 += B[c][j] * B[c][j];
                C[c][j] -= mu2; ss2 += C[c][j] * C[c][j];
            }
        }
#pragma unroll
        for (int off = 1; off < 64; off <<= 1) {
            ss0 += __shfl_xor(ss0, off);
            ss1 += __shfl_xor(ss1, off);
            ss2 += __shfl_xor(ss2, off);
        }
        const float rs0 = 1.0f / sqrtf(ss0 * INV_H + EPS);
        const float rs1 = 1.0f / sqrtf(ss1 * INV_H + EPS);
        const float rs2 = 1.0f / sqrtf(ss2 * INV_H + EPS);

        // ---- normalize + affine + fp8 + store; gamma/beta shared per chunk ----
#pragma unroll
        for (int c = 0; c < CHUNKS; ++c) {
            const int col = col0 + c * 256;
            const float4 gv = *reinterpret_cast<const float4*>(gamma + col);
            const float4 tv = *reinterpret_cast<const float4*>(beta + col);
            quantChunk(A[c], rs0, gv, tv, out_q + b0 + col, localAmax);
            quantChunk(B[c], rs1, gv, tv, out_q + b1 + col, localAmax);
            quantChunk(C[c], rs2, gv, tv, out_q + b2 + col, localAmax);
        }
    }

    // tail rows (n_rows % 3): single-row path
    for (int row = 3 * triples + gw; row < n_rows; row += gwaves)
        processOneRow(row, col0, x, residual, bias, gamma, beta,
                      out_bda, out_q, localAmax);

    // ---- block amax -> one device-scope atomic per block ----
    float m = waveReduceMax(localAmax);
    if (lane == 0) red[wid] = m;
    __syncthreads();
    if (tid == 0) {
        const float bm = fmaxf(fmaxf(red[0], red[1]), fmaxf(red[2], red[3]));
        atomicMax(out_amax, __float_as_uint(bm));   // all values >= 0
    }
}

extern "C" void kernel_launch(void* const* d_in, const int* in_sizes, int n_in,
                              void* d_out, int out_size, void* d_ws, size_t ws_size,
                              hipStream_t stream) {
    const float* x        = (const float*)d_in[0];
    const float* bias     = (const float*)d_in[1];
    const float* residual = (const float*)d_in[2];
    const float* gamma    = (const float*)d_in[3];
    const float* beta     = (const float*)d_in[4];

    const int n_elems = in_sizes[0];          // B*S*H
    const int n_rows = n_elems / H;           // 32768

    float* out_bda = (float*)d_out;
    float* out_q   = out_bda + (size_t)n_elems;
    unsigned int* out_amax = (unsigned int*)(out_bda + 2 * (size_t)n_elems);

    // zero the amax slot each launch (deterministic across graph replays)
    hipMemsetAsync((void*)out_amax, 0, sizeof(unsigned int), stream);

    // 1024 blocks x 4 waves = 4096 waves, 3 rows/wave/iter; 4 blocks/CU
    // resident (waves_per_eu pinned to 4 -> 128-VGPR budget).
    int blocks = 1024;
    int need = (n_rows / 3 + 3) / 4;
    if (need < blocks) blocks = (need > 0) ? need : 1;

    fused_bda_ln_fp8<<<blocks, 256, 0, stream>>>(
        x, bias, residual, gamma, beta, out_bda, out_q, out_amax, n_rows);
}

// Round 8
// 112.361 us; speedup vs baseline: 1.2213x; 1.2213x over previous
//
#include <hip/hip_runtime.h>

// BiasAddLayerNormFP8: bda = residual + (x + bias); LayerNorm over H=1024;
// outputs: [bda2 f32 | fp8(ln) dequantized to f32 | amax scalar], all float32.
//
// R8: R5's proven 2-row straight-line structure, grid raised 1024 -> 2048
// blocks. Structure compiles to VGPR=64 (R3/R4/R6 evidence) -> HW supports
// 8 blocks/CU = 32 waves/CU; R5 only launched enough blocks for 16 waves/CU.
// Single-variable change vs R5's 113.6us: double the resident waves (TLP).

constexpr int H = 1024;
constexpr int CHUNKS = 4;            // 4 x float4 x 64 lanes = 1024 cols
constexpr float EPS = 1e-5f;
constexpr float FP8_MAX = 448.0f;
constexpr float INV_H = 1.0f / 1024.0f;

__device__ __forceinline__ float waveAllReduceSum(float v) {
#pragma unroll
    for (int off = 1; off < 64; off <<= 1) v += __shfl_xor(v, off);
    return v;
}

__device__ __forceinline__ float waveReduceMax(float v) {
#pragma unroll
    for (int off = 32; off > 0; off >>= 1) v = fmaxf(v, __shfl_down(v, off));
    return v;
}

__device__ __forceinline__ void quantChunk(
    const float (&d)[4], float rsigma, const float4& gv, const float4& tv,
    float* __restrict__ dst, float& localAmax)
{
    const float l0 = d[0] * rsigma * gv.x + tv.x;
    const float l1 = d[1] * rsigma * gv.y + tv.y;
    const float l2 = d[2] * rsigma * gv.z + tv.z;
    const float l3 = d[3] * rsigma * gv.w + tv.w;

    localAmax = fmaxf(localAmax,
        fmaxf(fmaxf(fabsf(l0), fabsf(l1)), fmaxf(fabsf(l2), fabsf(l3))));

    const float c0 = fminf(fmaxf(l0, -FP8_MAX), FP8_MAX);
    const float c1 = fminf(fmaxf(l1, -FP8_MAX), FP8_MAX);
    const float c2 = fminf(fmaxf(l2, -FP8_MAX), FP8_MAX);
    const float c3 = fminf(fmaxf(l3, -FP8_MAX), FP8_MAX);
    const int p01 = __builtin_amdgcn_cvt_pk_fp8_f32(c0, c1, 0, false);
    const int p23 = __builtin_amdgcn_cvt_pk_fp8_f32(c2, c3, 0, false);
    float4 qv;
    qv.x = __builtin_amdgcn_cvt_f32_fp8(p01, 0);
    qv.y = __builtin_amdgcn_cvt_f32_fp8(p01, 1);
    qv.z = __builtin_amdgcn_cvt_f32_fp8(p23, 0);
    qv.w = __builtin_amdgcn_cvt_f32_fp8(p23, 1);
    *reinterpret_cast<float4*>(dst) = qv;
}

// Single-row path (tail only; never runs for even n_rows). Same numerics.
__device__ __forceinline__ void processOneRow(
    int row, int col0,
    const float* __restrict__ x, const float* __restrict__ residual,
    const float* __restrict__ bias, const float* __restrict__ gamma,
    const float* __restrict__ beta,
    float* __restrict__ out_bda, float* __restrict__ out_q, float& localAmax)
{
    const size_t rbase = (size_t)row * H;
    float bda[CHUNKS][4];
    float s = 0.0f;
#pragma unroll
    for (int c = 0; c < CHUNKS; ++c) {
        const int col = col0 + c * 256;
        const float4 xv = *reinterpret_cast<const float4*>(x + rbase + col);
        const float4 rv = *reinterpret_cast<const float4*>(residual + rbase + col);
        const float4 bv = *reinterpret_cast<const float4*>(bias + col);
        bda[c][0] = rv.x + (xv.x + bv.x);
        bda[c][1] = rv.y + (xv.y + bv.y);
        bda[c][2] = rv.z + (xv.z + bv.z);
        bda[c][3] = rv.w + (xv.w + bv.w);
        *reinterpret_cast<float4*>(out_bda + rbase + col) =
            make_float4(bda[c][0], bda[c][1], bda[c][2], bda[c][3]);
        s += (bda[c][0] + bda[c][1]) + (bda[c][2] + bda[c][3]);
    }
    const float mu = waveAllReduceSum(s) * INV_H;
    float ss = 0.0f;
#pragma unroll
    for (int c = 0; c < CHUNKS; ++c)
#pragma unroll
        for (int j = 0; j < 4; ++j) { bda[c][j] -= mu; ss += bda[c][j] * bda[c][j]; }
    ss = waveAllReduceSum(ss);
    const float rsigma = 1.0f / sqrtf(ss * INV_H + EPS);
#pragma unroll
    for (int c = 0; c < CHUNKS; ++c) {
        const int col = col0 + c * 256;
        const float4 gv = *reinterpret_cast<const float4*>(gamma + col);
        const float4 tv = *reinterpret_cast<const float4*>(beta + col);
        quantChunk(bda[c], rsigma, gv, tv, out_q + rbase + col, localAmax);
    }
}

__global__ __launch_bounds__(256, 4) void fused_bda_ln_fp8(
    const float* __restrict__ x,
    const float* __restrict__ bias,
    const float* __restrict__ residual,
    const float* __restrict__ gamma,
    const float* __restrict__ beta,
    float* __restrict__ out_bda,
    float* __restrict__ out_q,
    unsigned int* __restrict__ out_amax,
    int n_rows)
{
    const int tid = threadIdx.x;      // 256 threads = 4 waves
    const int lane = tid & 63;
    const int wid = tid >> 6;
    const int col0 = lane * 4;
    const int gw = blockIdx.x * 4 + wid;     // global wave id
    const int gwaves = gridDim.x * 4;

    float localAmax = 0.0f;
    __shared__ float red[4];

    const int pairs = n_rows >> 1;

#pragma unroll 1
    for (int p = gw; p < pairs; p += gwaves) {
        const size_t b0 = (size_t)(2 * p) * H;
        const size_t b1 = b0 + H;

        // ---- issue ALL 16 loads back-to-back (one basic block, no branches) ----
        float4 xa[CHUNKS], ra[CHUNKS], xb[CHUNKS], rb[CHUNKS];
#pragma unroll
        for (int c = 0; c < CHUNKS; ++c) {
            const int col = col0 + c * 256;
            xa[c] = *reinterpret_cast<const float4*>(x + b0 + col);
            ra[c] = *reinterpret_cast<const float4*>(residual + b0 + col);
            xb[c] = *reinterpret_cast<const float4*>(x + b1 + col);
            rb[c] = *reinterpret_cast<const float4*>(residual + b1 + col);
        }

        // ---- consume: bda for both rows (row0's loads complete first) ----
        float A[CHUNKS][4], B[CHUNKS][4];
        float s0 = 0.0f, s1 = 0.0f;
#pragma unroll
        for (int c = 0; c < CHUNKS; ++c) {
            const int col = col0 + c * 256;
            const float4 bv = *reinterpret_cast<const float4*>(bias + col);
            A[c][0] = ra[c].x + (xa[c].x + bv.x);
            A[c][1] = ra[c].y + (xa[c].y + bv.y);
            A[c][2] = ra[c].z + (xa[c].z + bv.z);
            A[c][3] = ra[c].w + (xa[c].w + bv.w);
            B[c][0] = rb[c].x + (xb[c].x + bv.x);
            B[c][1] = rb[c].y + (xb[c].y + bv.y);
            B[c][2] = rb[c].z + (xb[c].z + bv.z);
            B[c][3] = rb[c].w + (xb[c].w + bv.w);
            *reinterpret_cast<float4*>(out_bda + b0 + col) =
                make_float4(A[c][0], A[c][1], A[c][2], A[c][3]);
            *reinterpret_cast<float4*>(out_bda + b1 + col) =
                make_float4(B[c][0], B[c][1], B[c][2], B[c][3]);
            s0 += (A[c][0] + A[c][1]) + (A[c][2] + A[c][3]);
            s1 += (B[c][0] + B[c][1]) + (B[c][2] + B[c][3]);
        }

        // ---- mean: two independent butterflies, explicitly interleaved ----
#pragma unroll
        for (int off = 1; off < 64; off <<= 1) {
            s0 += __shfl_xor(s0, off);
            s1 += __shfl_xor(s1, off);
        }
        const float mu0 = s0 * INV_H;
        const float mu1 = s1 * INV_H;

        // ---- variance, two-pass, both rows ----
        float ss0 = 0.0f, ss1 = 0.0f;
#pragma unroll
        for (int c = 0; c < CHUNKS; ++c) {
#pragma unroll
            for (int j = 0; j < 4; ++j) {
                A[c][j] -= mu0; ss0 += A[c][j] * A[c][j];
                B[c][j] -= mu1; ss1 += B[c][j] * B[c][j];
            }
        }
#pragma unroll
        for (int off = 1; off < 64; off <<= 1) {
            ss0 += __shfl_xor(ss0, off);
            ss1 += __shfl_xor(ss1, off);
        }
        const float rs0 = 1.0f / sqrtf(ss0 * INV_H + EPS);
        const float rs1 = 1.0f / sqrtf(ss1 * INV_H + EPS);

        // ---- normalize + affine + fp8 + store; gamma/beta shared per chunk ----
#pragma unroll
        for (int c = 0; c < CHUNKS; ++c) {
            const int col = col0 + c * 256;
            const float4 gv = *reinterpret_cast<const float4*>(gamma + col);
            const float4 tv = *reinterpret_cast<const float4*>(beta + col);
            quantChunk(A[c], rs0, gv, tv, out_q + b0 + col, localAmax);
            quantChunk(B[c], rs1, gv, tv, out_q + b1 + col, localAmax);
        }
    }

    // tail (odd n_rows only; never runs in this benchmark)
    for (int row = 2 * pairs + gw; row < n_rows; row += gwaves)
        processOneRow(row, col0, x, residual, bias, gamma, beta,
                      out_bda, out_q, localAmax);

    // ---- block amax -> one device-scope atomic per block ----
    float m = waveReduceMax(localAmax);
    if (lane == 0) red[wid] = m;
    __syncthreads();
    if (tid == 0) {
        const float bm = fmaxf(fmaxf(red[0], red[1]), fmaxf(red[2], red[3]));
        atomicMax(out_amax, __float_as_uint(bm));   // all values >= 0
    }
}

extern "C" void kernel_launch(void* const* d_in, const int* in_sizes, int n_in,
                              void* d_out, int out_size, void* d_ws, size_t ws_size,
                              hipStream_t stream) {
    const float* x        = (const float*)d_in[0];
    const float* bias     = (const float*)d_in[1];
    const float* residual = (const float*)d_in[2];
    const float* gamma    = (const float*)d_in[3];
    const float* beta     = (const float*)d_in[4];

    const int n_elems = in_sizes[0];          // B*S*H
    const int n_rows = n_elems / H;           // 32768

    float* out_bda = (float*)d_out;
    float* out_q   = out_bda + (size_t)n_elems;
    unsigned int* out_amax = (unsigned int*)(out_bda + 2 * (size_t)n_elems);

    // zero the amax slot each launch (deterministic across graph replays)
    hipMemsetAsync((void*)out_amax, 0, sizeof(unsigned int), stream);

    // 2048 blocks x 4 waves = 8192 waves, 2 rows/wave/iter -> 2 iterations.
    // At VGPR=64 the HW fits 8 blocks/CU -> 32 waves/CU (vs R5's 16).
    int blocks = (n_rows / 2 + 3) / 4;
    if (blocks > 2048) blocks = 2048;

    fused_bda_ln_fp8<<<blocks, 256, 0, stream>>>(
        x, bias, residual, gamma, beta, out_bda, out_q, out_amax, n_rows);
}